// Round 1
// baseline (15904.222 us; speedup 1.0000x reference)
//
#include <hip/hip_runtime.h>
#include <math.h>

// Problem constants (match reference)
constexpr int kP  = 3;
constexpr int kN  = 50000;
constexpr int kE  = 256000;
constexpr int kC  = 5;
constexpr int kF  = 68;    // F_IN + F_NODE
constexpr int kF2 = 136;   // 2*F
constexpr int kFE = 16;    // F_EDGE
constexpr int kFN = 64;    // F_NODE

// Exact tanh via exp: (e^{2x}-1)/(e^{2x}+1). Clamp so e^{2x} stays finite.
__device__ __forceinline__ float fast_tanh(float x) {
  float t = fminf(fmaxf(x, -15.f), 15.f);
  float e = __expf(2.f * t);
  return (e - 1.f) / (e + 1.f);
}

// ---------------------------------------------------------------------------
// Edge kernel: one thread per edge. Computes the per-class softmax weight and
// atomically scatters w[c] * x_j into aggr[dst].
// Weight tensors are indexed uniformly across the wave -> scalar loads.
// ---------------------------------------------------------------------------
__global__ __launch_bounds__(256) void edge_kernel(
    const float* __restrict__ x,     // [N, C, F]   (this plane)
    const int*   __restrict__ ei,    // [2, E]      (this plane)
    const float* __restrict__ We1,   // [C, 16, 136]
    const float* __restrict__ be1,   // [C, 16]
    const float* __restrict__ We2,   // [C, 16]
    const float* __restrict__ be2,   // [C]
    float*       __restrict__ aggr)  // [N, C, F]
{
  int e = blockIdx.x * 256 + threadIdx.x;
  if (e >= kE) return;

  int src = ei[e];        // x_j
  int dst = ei[kE + e];   // x_i (target; also scatter destination)

  const float* xi = x + (size_t)dst * (kC * kF);
  const float* xj = x + (size_t)src * (kC * kF);

  float logits[kC];

  for (int c = 0; c < kC; ++c) {
    const float* Wc = We1 + c * (kFE * kF2);
    const float4* a4 = reinterpret_cast<const float4*>(xi + c * kF);
    const float4* b4 = reinterpret_cast<const float4*>(xj + c * kF);

    float h[kFE];
#pragma unroll
    for (int g = 0; g < kFE; ++g) h[g] = be1[c * kFE + g];

    for (int q = 0; q < kF / 4; ++q) {  // 17 iterations
      float4 a = a4[q];
      float4 b = b4[q];
#pragma unroll
      for (int g = 0; g < kFE; ++g) {
        const float* wr  = Wc + g * kF2 + 4 * q;   // W[c][g][4q .. 4q+3]
        const float* wr2 = wr + kF;                // W[c][g][68+4q ...]
        float acc = h[g];
        acc = fmaf(wr[0],  a.x, acc);
        acc = fmaf(wr[1],  a.y, acc);
        acc = fmaf(wr[2],  a.z, acc);
        acc = fmaf(wr[3],  a.w, acc);
        acc = fmaf(wr2[0], b.x, acc);
        acc = fmaf(wr2[1], b.y, acc);
        acc = fmaf(wr2[2], b.z, acc);
        acc = fmaf(wr2[3], b.w, acc);
        h[g] = acc;
      }
    }

    float lg = be2[c];
#pragma unroll
    for (int g = 0; g < kFE; ++g)
      lg = fmaf(We2[c * kFE + g], fast_tanh(h[g]), lg);
    logits[c] = lg;
  }

  // Softmax over the class dimension
  float m = logits[0];
#pragma unroll
  for (int c = 1; c < kC; ++c) m = fmaxf(m, logits[c]);
  float w[kC];
  float s = 0.f;
#pragma unroll
  for (int c = 0; c < kC; ++c) {
    w[c] = __expf(logits[c] - m);
    s += w[c];
  }
  float inv = 1.f / s;

  // Scatter msg = w[c] * x_j into aggr[dst]
  float* agd = aggr + (size_t)dst * (kC * kF);
  for (int c = 0; c < kC; ++c) {
    float wc = w[c] * inv;
    const float* xjc = xj + c * kF;
    float* ag = agd + c * kF;
    for (int f = 0; f < kF; ++f) {
      atomicAdd(&ag[f], wc * xjc[f]);
    }
  }
}

// ---------------------------------------------------------------------------
// Node kernel: one thread per (node, class). u_in = [x[n,c,:], aggr[n,c,:]],
// h2 = tanh(Wn1 @ u_in + bn1), out = tanh(Wn2 @ h2 + bn2).
// ---------------------------------------------------------------------------
__global__ __launch_bounds__(256) void node_kernel(
    const float* __restrict__ x,     // [N, C, F]
    const float* __restrict__ aggr,  // [N, C, F]
    const float* __restrict__ Wn1,   // [C, 64, 136]
    const float* __restrict__ bn1,   // [C, 64]
    const float* __restrict__ Wn2,   // [C, 64, 64]
    const float* __restrict__ bn2,   // [C, 64]
    float*       __restrict__ out)   // [N, C, 64]
{
  int n = blockIdx.x * 256 + threadIdx.x;
  int c = blockIdx.y;
  if (n >= kN) return;

  const float4* a4 = reinterpret_cast<const float4*>(x    + ((size_t)n * kC + c) * kF);
  const float4* g4 = reinterpret_cast<const float4*>(aggr + ((size_t)n * kC + c) * kF);
  const float* W1 = Wn1 + c * (kFN * kF2);

  float h[kFN];
#pragma unroll
  for (int g = 0; g < kFN; ++g) h[g] = bn1[c * kFN + g];

  for (int q = 0; q < kF / 4; ++q) {  // 17 iterations over both halves
    float4 a = a4[q];
    float4 b = g4[q];
#pragma unroll
    for (int g = 0; g < kFN; ++g) {
      const float* wr  = W1 + g * kF2 + 4 * q;  // first-half weights (x part)
      const float* wr2 = wr + kF;               // second-half weights (aggr)
      float acc = h[g];
      acc = fmaf(wr[0],  a.x, acc);
      acc = fmaf(wr[1],  a.y, acc);
      acc = fmaf(wr[2],  a.z, acc);
      acc = fmaf(wr[3],  a.w, acc);
      acc = fmaf(wr2[0], b.x, acc);
      acc = fmaf(wr2[1], b.y, acc);
      acc = fmaf(wr2[2], b.z, acc);
      acc = fmaf(wr2[3], b.w, acc);
      h[g] = acc;
    }
  }

#pragma unroll
  for (int g = 0; g < kFN; ++g) h[g] = fast_tanh(h[g]);

  const float* W2 = Wn2 + c * (kFN * kFN);
  float* op = out + ((size_t)n * kC + c) * kFN;
  for (int g2 = 0; g2 < kFN; ++g2) {
    float acc = bn2[c * kFN + g2];
    const float* wr = W2 + g2 * kFN;
#pragma unroll
    for (int k = 0; k < kFN; ++k) acc = fmaf(wr[k], h[k], acc);
    op[g2] = fast_tanh(acc);
  }
}

// ---------------------------------------------------------------------------
extern "C" void kernel_launch(void* const* d_in, const int* in_sizes, int n_in,
                              void* d_out, int out_size, void* d_ws, size_t ws_size,
                              hipStream_t stream) {
  const float* x   = (const float*)d_in[0];   // [P, N, C, F]
  const int*   ei  = (const int*)  d_in[1];   // [P, 2, E] (int32)
  const float* We1 = (const float*)d_in[2];   // [P, C, 16, 136]
  const float* be1 = (const float*)d_in[3];   // [P, C, 16]
  const float* We2 = (const float*)d_in[4];   // [P, C, 1, 16]
  const float* be2 = (const float*)d_in[5];   // [P, C, 1]
  const float* Wn1 = (const float*)d_in[6];   // [P, C, 64, 136]
  const float* bn1 = (const float*)d_in[7];   // [P, C, 64]
  const float* Wn2 = (const float*)d_in[8];   // [P, C, 64, 64]
  const float* bn2 = (const float*)d_in[9];   // [P, C, 64]
  float* out = (float*)d_out;                 // [P, N, C, 64]

  float* aggr = (float*)d_ws;                 // [N, C, F] per-plane scratch
  const size_t planeX = (size_t)kN * kC * kF; // floats per plane of x/aggr

  for (int p = 0; p < kP; ++p) {
    hipMemsetAsync(aggr, 0, planeX * sizeof(float), stream);

    edge_kernel<<<(kE + 255) / 256, 256, 0, stream>>>(
        x + p * planeX,
        ei + (size_t)p * 2 * kE,
        We1 + (size_t)p * kC * kFE * kF2,
        be1 + (size_t)p * kC * kFE,
        We2 + (size_t)p * kC * kFE,
        be2 + (size_t)p * kC,
        aggr);

    node_kernel<<<dim3((kN + 255) / 256, kC), 256, 0, stream>>>(
        x + p * planeX,
        aggr,
        Wn1 + (size_t)p * kC * kFN * kF2,
        bn1 + (size_t)p * kC * kFN,
        Wn2 + (size_t)p * kC * kFN * kFN,
        bn2 + (size_t)p * kC * kFN,
        out + (size_t)p * kN * kC * kFN);
  }
}

// Round 2
// 2641.957 us; speedup vs baseline: 6.0199x; 6.0199x over previous
//
#include <hip/hip_runtime.h>
#include <math.h>

// Problem constants (match reference)
constexpr int kP  = 3;
constexpr int kN  = 50000;
constexpr int kE  = 256000;
constexpr int kC  = 5;
constexpr int kF  = 68;    // F_IN + F_NODE
constexpr int kF2 = 136;   // 2*F
constexpr int kFE = 16;    // F_EDGE
constexpr int kFN = 64;    // F_NODE
constexpr int kOfsStride = 50004;  // (N+1) rounded up to mult of 4 ints

__device__ __forceinline__ float fast_tanh(float x) {
  float t = fminf(fmaxf(x, -15.f), 15.f);
  float e = __expf(2.f * t);
  return (e - 1.f) / (e + 1.f);
}

// ---------------------------------------------------------------------------
// 1) Histogram of in-degrees (all planes): counts[p][dst]++
// ---------------------------------------------------------------------------
__global__ __launch_bounds__(256) void hist_kernel(
    const int* __restrict__ ei,   // [P, 2, E]
    int* __restrict__ counts)     // [P, N]
{
  int p = blockIdx.y;
  int e = blockIdx.x * 256 + threadIdx.x;
  if (e >= kE) return;
  int dst = ei[(size_t)p * 2 * kE + kE + e];
  atomicAdd(&counts[p * kN + dst], 1);
}

// ---------------------------------------------------------------------------
// 2) Exclusive scan per plane (one 1024-thread block per plane).
//    Writes offsets[p][0..N] and initializes cursor[p][0..N-1] = offsets.
// ---------------------------------------------------------------------------
__global__ __launch_bounds__(1024) void scan_kernel(
    const int* __restrict__ counts,  // [P, N]
    int* __restrict__ offsets,       // [P, kOfsStride]
    int* __restrict__ cursor)        // [P, N]
{
  int p = blockIdx.x;
  const int* cnt = counts + p * kN;
  int* ofs = offsets + p * kOfsStride;
  int* cur = cursor + p * kN;
  __shared__ int buf[1024];
  __shared__ int carry_s;
  int tid = threadIdx.x;
  if (tid == 0) carry_s = 0;
  __syncthreads();
  for (int base = 0; base < kN; base += 1024) {
    int i = base + tid;
    int v = (i < kN) ? cnt[i] : 0;
    buf[tid] = v;
    __syncthreads();
    for (int d = 1; d < 1024; d <<= 1) {
      int t = (tid >= d) ? buf[tid - d] : 0;
      __syncthreads();
      buf[tid] += t;
      __syncthreads();
    }
    int incl = buf[tid];
    int carry = carry_s;
    if (i < kN) {
      int excl = carry + incl - v;
      ofs[i] = excl;
      cur[i] = excl;
    }
    __syncthreads();
    if (tid == 1023) carry_s = carry + incl;
    __syncthreads();
  }
  if (tid == 0) ofs[kN] = carry_s;
}

// ---------------------------------------------------------------------------
// 3) Per-node edge-layer-1 precompute:
//    yi[n,c,g] = We1[c][g][0:68]   . x[n,c,:]
//    yj[n,c,g] = We1[c][g][68:136] . x[n,c,:]
// ---------------------------------------------------------------------------
__global__ __launch_bounds__(256) void pre_kernel(
    const float* __restrict__ x,    // [N, C, F] (this plane)
    const float* __restrict__ We1,  // [C, 16, 136]
    float* __restrict__ yi,         // [N, C, 16]
    float* __restrict__ yj)         // [N, C, 16]
{
  int n = blockIdx.x * 256 + threadIdx.x;
  int c = blockIdx.y;
  if (n >= kN) return;

  const float4* xr = reinterpret_cast<const float4*>(x + ((size_t)n * kC + c) * kF);
  const float* Wc = We1 + c * (kFE * kF2);

  float ai[kFE], aj[kFE];
#pragma unroll
  for (int g = 0; g < kFE; ++g) { ai[g] = 0.f; aj[g] = 0.f; }

  for (int q = 0; q < kF / 4; ++q) {  // 17
    float4 v = xr[q];
#pragma unroll
    for (int g = 0; g < kFE; ++g) {
      const float* wi = Wc + g * kF2 + 4 * q;
      const float* wj = wi + kF;
      float a = ai[g];
      a = fmaf(wi[0], v.x, a); a = fmaf(wi[1], v.y, a);
      a = fmaf(wi[2], v.z, a); a = fmaf(wi[3], v.w, a);
      ai[g] = a;
      float b = aj[g];
      b = fmaf(wj[0], v.x, b); b = fmaf(wj[1], v.y, b);
      b = fmaf(wj[2], v.z, b); b = fmaf(wj[3], v.w, b);
      aj[g] = b;
    }
  }

  float4* oi = reinterpret_cast<float4*>(yi + ((size_t)n * kC + c) * kFE);
  float4* oj = reinterpret_cast<float4*>(yj + ((size_t)n * kC + c) * kFE);
#pragma unroll
  for (int k = 0; k < 4; ++k) {
    oi[k] = make_float4(ai[4*k], ai[4*k+1], ai[4*k+2], ai[4*k+3]);
    oj[k] = make_float4(aj[4*k], aj[4*k+1], aj[4*k+2], aj[4*k+3]);
  }
}

// ---------------------------------------------------------------------------
// 4) Edge kernel: softmax weights from precomputed yi/yj, scattered into the
//    CSR slot claimed via cursor (int atomic). No float atomics anywhere.
// ---------------------------------------------------------------------------
__global__ __launch_bounds__(256) void edge_kernel(
    const int*   __restrict__ ei,         // [2, E] (this plane)
    const float* __restrict__ yi,         // [N, C, 16]
    const float* __restrict__ yj,         // [N, C, 16]
    const float* __restrict__ be1,        // [C, 16]
    const float* __restrict__ We2,        // [C, 16]
    const float* __restrict__ be2,        // [C]
    int*         __restrict__ cursor,     // [N] (this plane)
    int*         __restrict__ sorted_src, // [E]
    float*       __restrict__ w_sorted)   // [E, C]
{
  int e = blockIdx.x * 256 + threadIdx.x;
  if (e >= kE) return;
  int src = ei[e];
  int dst = ei[kE + e];

  const float* yid = yi + (size_t)dst * (kC * kFE);
  const float* yjs = yj + (size_t)src * (kC * kFE);

  float logits[kC];
#pragma unroll
  for (int c = 0; c < kC; ++c) {
    const float4* a = reinterpret_cast<const float4*>(yid + c * kFE);
    const float4* b = reinterpret_cast<const float4*>(yjs + c * kFE);
    float lg = be2[c];
#pragma unroll
    for (int qq = 0; qq < 4; ++qq) {
      float4 av = a[qq];
      float4 bv = b[qq];
      const float* bb = be1 + c * kFE + 4 * qq;
      const float* w2 = We2 + c * kFE + 4 * qq;
      lg = fmaf(w2[0], fast_tanh(av.x + bv.x + bb[0]), lg);
      lg = fmaf(w2[1], fast_tanh(av.y + bv.y + bb[1]), lg);
      lg = fmaf(w2[2], fast_tanh(av.z + bv.z + bb[2]), lg);
      lg = fmaf(w2[3], fast_tanh(av.w + bv.w + bb[3]), lg);
    }
    logits[c] = lg;
  }

  float m = logits[0];
#pragma unroll
  for (int c = 1; c < kC; ++c) m = fmaxf(m, logits[c]);
  float wgt[kC];
  float s = 0.f;
#pragma unroll
  for (int c = 0; c < kC; ++c) { wgt[c] = __expf(logits[c] - m); s += wgt[c]; }
  float inv = 1.f / s;

  int pos = atomicAdd(&cursor[dst], 1);
  sorted_src[pos] = src;
#pragma unroll
  for (int c = 0; c < kC; ++c) w_sorted[(size_t)pos * kC + c] = wgt[c] * inv;
}

// ---------------------------------------------------------------------------
// 5) Fused aggregate + node MLP. Thread per (n, c). The aggregated float4
//    chunk feeds Wn1 directly — aggr never hits memory.
// ---------------------------------------------------------------------------
__global__ __launch_bounds__(256) void node_fused_kernel(
    const float* __restrict__ x,          // [N, C, F] (this plane)
    const int*   __restrict__ offsets,    // [N+1] (this plane)
    const int*   __restrict__ sorted_src, // [E]
    const float* __restrict__ w_sorted,   // [E, C]
    const float* __restrict__ Wn1,        // [C, 64, 136]
    const float* __restrict__ bn1,        // [C, 64]
    const float* __restrict__ Wn2,        // [C, 64, 64]
    const float* __restrict__ bn2,        // [C, 64]
    float*       __restrict__ out)        // [N, C, 64] (this plane)
{
  int n = blockIdx.x * 256 + threadIdx.x;
  int c = blockIdx.y;
  if (n >= kN) return;

  int beg = offsets[n];
  int end = offsets[n + 1];

  const float4* xr = reinterpret_cast<const float4*>(x + ((size_t)n * kC + c) * kF);
  const float* W1 = Wn1 + c * (kFN * kF2);

  float h[kFN];
#pragma unroll
  for (int g = 0; g < kFN; ++g) h[g] = bn1[c * kFN + g];

  for (int q = 0; q < kF / 4; ++q) {  // 17
    float4 a = xr[q];
    float4 gg = make_float4(0.f, 0.f, 0.f, 0.f);
    for (int s = beg; s < end; ++s) {
      int sj = sorted_src[s];
      float w = w_sorted[(size_t)s * kC + c];
      float4 v = reinterpret_cast<const float4*>(x + ((size_t)sj * kC + c) * kF)[q];
      gg.x = fmaf(w, v.x, gg.x);
      gg.y = fmaf(w, v.y, gg.y);
      gg.z = fmaf(w, v.z, gg.z);
      gg.w = fmaf(w, v.w, gg.w);
    }
#pragma unroll
    for (int g = 0; g < kFN; ++g) {
      const float* wr  = W1 + g * kF2 + 4 * q;  // x half
      const float* wr2 = wr + kF;               // aggr half
      float acc = h[g];
      acc = fmaf(wr[0],  a.x,  acc);
      acc = fmaf(wr[1],  a.y,  acc);
      acc = fmaf(wr[2],  a.z,  acc);
      acc = fmaf(wr[3],  a.w,  acc);
      acc = fmaf(wr2[0], gg.x, acc);
      acc = fmaf(wr2[1], gg.y, acc);
      acc = fmaf(wr2[2], gg.z, acc);
      acc = fmaf(wr2[3], gg.w, acc);
      h[g] = acc;
    }
  }

#pragma unroll
  for (int g = 0; g < kFN; ++g) h[g] = fast_tanh(h[g]);

  const float* W2 = Wn2 + c * (kFN * kFN);
  float* op = out + ((size_t)n * kC + c) * kFN;
  for (int g2 = 0; g2 < kFN; ++g2) {
    float acc = bn2[c * kFN + g2];
    const float* wr = W2 + g2 * kFN;
#pragma unroll
    for (int k = 0; k < kFN; ++k) acc = fmaf(wr[k], h[k], acc);
    op[g2] = fast_tanh(acc);
  }
}

// ---------------------------------------------------------------------------
extern "C" void kernel_launch(void* const* d_in, const int* in_sizes, int n_in,
                              void* d_out, int out_size, void* d_ws, size_t ws_size,
                              hipStream_t stream) {
  const float* x   = (const float*)d_in[0];   // [P, N, C, F]
  const int*   ei  = (const int*)  d_in[1];   // [P, 2, E] (int32 from harness)
  const float* We1 = (const float*)d_in[2];   // [P, C, 16, 136]
  const float* be1 = (const float*)d_in[3];   // [P, C, 16]
  const float* We2 = (const float*)d_in[4];   // [P, C, 1, 16]
  const float* be2 = (const float*)d_in[5];   // [P, C, 1]
  const float* Wn1 = (const float*)d_in[6];   // [P, C, 64, 136]
  const float* bn1 = (const float*)d_in[7];   // [P, C, 64]
  const float* Wn2 = (const float*)d_in[8];   // [P, C, 64, 64]
  const float* bn2 = (const float*)d_in[9];   // [P, C, 64]
  float* out = (float*)d_out;                 // [P, N, C, 64]

  // Workspace layout (all 16B-aligned; ~40 MB total, ws was >=68 MB in R1)
  int* counts  = (int*)d_ws;                       // P*N ints
  int* offsets = counts + kP * kN;                 // P*kOfsStride ints
  int* cursor  = offsets + kP * kOfsStride;        // P*N ints
  int* sorted_src = cursor + kP * kN;              // E ints (per-plane reuse)
  float* w_sorted = (float*)(sorted_src + kE);     // E*C floats (reuse)
  float* yi = w_sorted + (size_t)kE * kC;          // N*C*16 floats (reuse)
  float* yj = yi + (size_t)kN * kC * kFE;          // N*C*16 floats (reuse)

  const size_t planeX = (size_t)kN * kC * kF;

  hipMemsetAsync(counts, 0, (size_t)kP * kN * sizeof(int), stream);
  hist_kernel<<<dim3(kE / 256, kP), 256, 0, stream>>>(ei, counts);
  scan_kernel<<<kP, 1024, 0, stream>>>(counts, offsets, cursor);

  for (int p = 0; p < kP; ++p) {
    const float* xp = x + p * planeX;

    pre_kernel<<<dim3((kN + 255) / 256, kC), 256, 0, stream>>>(
        xp, We1 + (size_t)p * kC * kFE * kF2, yi, yj);

    edge_kernel<<<kE / 256, 256, 0, stream>>>(
        ei + (size_t)p * 2 * kE, yi, yj,
        be1 + (size_t)p * kC * kFE,
        We2 + (size_t)p * kC * kFE,
        be2 + (size_t)p * kC,
        cursor + p * kN, sorted_src, w_sorted);

    node_fused_kernel<<<dim3((kN + 255) / 256, kC), 256, 0, stream>>>(
        xp, offsets + p * kOfsStride, sorted_src, w_sorted,
        Wn1 + (size_t)p * kC * kFN * kF2,
        bn1 + (size_t)p * kC * kFN,
        Wn2 + (size_t)p * kC * kFN * kFN,
        bn2 + (size_t)p * kC * kFN,
        out + (size_t)p * kN * kC * kFN);
  }
}